// Round 3
// baseline (947.445 us; speedup 1.0000x reference)
//
#include <hip/hip_runtime.h>

#define N_PTS 131072
#define K_CODES 1024
#define DIM 64
#define DECAYF 0.99f
#define OMDF 0.01f
#define EPSF 1e-5f

// ---- d_out layout (float elements, reference return order) ----
#define OUT_ZQ      0                  // [N, D]
#define OUT_LOSS    8388608            // scalar
#define OUT_IDX     8388609            // [N] (indices as floats)
#define OUT_NEWEMB  8519681            // [K, D]
#define OUT_NEWCS   8585217            // [K]
#define OUT_NEWEMA  8586241            // [K, D]

// ---- ws layout (float elements) ----
#define WS_COUNTS   0                  // K floats (memset to 0 each launch)
#define WS_START    1024               // K ints
#define WS_CURSOR   2048               // K ints
#define WS_CS       3072               // K floats
#define WS_ENORM    4096               // K floats
#define WS_LOSSARR  5120               // 512 floats (per-argmin-block SSE partials)
#define WS_ORDER    6144               // N ints

__global__ __launch_bounds__(256) void enorm_kernel(const float* __restrict__ E,
                                                    float* __restrict__ enorm) {
    int k = blockIdx.x * blockDim.x + threadIdx.x;
    if (k < K_CODES) {
        const float4* e4 = (const float4*)(E + (size_t)k * DIM);
        float s = 0.f;
#pragma unroll
        for (int i = 0; i < 16; ++i) {
            float4 v = e4[i];
            s += v.x * v.x + v.y * v.y + v.z * v.z + v.w * v.w;
        }
        enorm[k] = s;
    }
}

// 1 row/thread, 256 threads/block, 512 blocks -> 8 waves/CU (2/SIMD).
// E is read via wave-uniform addresses -> compiler emits s_load (scalar
// cache/L2), broadcast operand comes from SGPR into v_fmac: NO LDS pipe use.
// Fused: z_q gather-write, commitment-loss block partial, counts histogram.
__global__ __launch_bounds__(256) void argmin_kernel(const float* __restrict__ z,
                                                     const float* __restrict__ E,
                                                     const float* __restrict__ enorm,
                                                     float* __restrict__ out_idx_f,
                                                     float* __restrict__ counts,
                                                     float* __restrict__ zq_out,
                                                     float* __restrict__ lossarr) {
    int row = blockIdx.x * 256 + threadIdx.x;

    float4 zr[16];
    float znorm = 0.f;
    {
        const float4* z4 = (const float4*)(z + (size_t)row * DIM);
#pragma unroll
        for (int i = 0; i < 16; ++i) {
            float4 v = z4[i];
            zr[i] = v;
            znorm += v.x * v.x + v.y * v.y + v.z * v.z + v.w * v.w;
        }
    }

    float best = INFINITY;
    int bidx = 0;

    for (int k = 0; k < K_CODES; ++k) {
        const float4* e4 = (const float4*)(E + (size_t)k * DIM);  // uniform addr
        float d0 = 0.f, d1 = 0.f, d2 = 0.f, d3 = 0.f;
#pragma unroll
        for (int i = 0; i < 16; ++i) {
            float4 ev = e4[i];
            d0 += zr[i].x * ev.x;
            d1 += zr[i].y * ev.y;
            d2 += zr[i].z * ev.z;
            d3 += zr[i].w * ev.w;
        }
        float s = enorm[k] - 2.f * ((d0 + d1) + (d2 + d3));
        if (s < best) { best = s; bidx = k; }
    }

    out_idx_f[row] = (float)bidx;
    atomicAdd(&counts[bidx], 1.0f);

    // z_q gather (E is L2-hot, 256 KB) + coalesced store
    {
        const float4* eb = (const float4*)(E + (size_t)bidx * DIM);
        float4* o4 = (float4*)(zq_out + (size_t)row * DIM);
#pragma unroll
        for (int i = 0; i < 16; ++i) o4[i] = eb[i];
    }

    // ||z-e||^2 = ||z||^2 + (||e||^2 - 2 z.e) = znorm + best
    float sse = znorm + best;
    __shared__ float red[256];
    red[threadIdx.x] = sse;
    __syncthreads();
    for (int st = 128; st > 0; st >>= 1) {
        if (threadIdx.x < st) red[threadIdx.x] += red[threadIdx.x + st];
        __syncthreads();
    }
    if (threadIdx.x == 0) lossarr[blockIdx.x] = red[0];
}

// One block of 1024: new_cluster_size, n, cs, and exclusive prefix sum of
// counts -> start/cursor arrays for the counting sort.
__global__ __launch_bounds__(1024) void scan_kernel(const float* __restrict__ cluster_size,
                                                    const float* __restrict__ counts,
                                                    float* __restrict__ ncs_out,
                                                    float* __restrict__ cs_ws,
                                                    int* __restrict__ start,
                                                    int* __restrict__ cursor) {
    int k = threadIdx.x;
    float cf = counts[k];
    float ncs = cluster_size[k] * DECAYF + OMDF * cf;
    ncs_out[k] = ncs;

    __shared__ float red[1024];
    __shared__ int pfx[1024];
    red[k] = ncs;
    pfx[k] = (int)cf;
    __syncthreads();
    for (int st = 512; st > 0; st >>= 1) {
        if (k < st) red[k] += red[k + st];
        __syncthreads();
    }
    float n = red[0];
    cs_ws[k] = (ncs + EPSF) / (n + (float)K_CODES * EPSF) * n;

    for (int off = 1; off < 1024; off <<= 1) {
        int add = (k >= off) ? pfx[k - off] : 0;
        __syncthreads();
        pfx[k] += add;
        __syncthreads();
    }
    int excl = pfx[k] - (int)cf;
    start[k] = excl;
    cursor[k] = excl;
}

__global__ __launch_bounds__(256) void scatter_kernel(const float* __restrict__ idx_f,
                                                      int* __restrict__ cursor,
                                                      int* __restrict__ order) {
    int row = blockIdx.x * 256 + threadIdx.x;
    int k = (int)idx_f[row];
    int p = atomicAdd(&cursor[k], 1);
    order[p] = row;
}

// One block (4 waves) per code: segment-sum the code's rows (no atomics),
// then fused new_ema / new_embeddings epilogue.
__global__ __launch_bounds__(256) void segsum_kernel(const float* __restrict__ z,
                                                     const float* __restrict__ ema,
                                                     const float* __restrict__ countsf,
                                                     const int* __restrict__ start,
                                                     const int* __restrict__ order,
                                                     const float* __restrict__ cs_ws,
                                                     float* __restrict__ newema_out,
                                                     float* __restrict__ newemb_out) {
    int k = blockIdx.x;
    int d = threadIdx.x & 63;
    int w = threadIdx.x >> 6;
    int base = start[k];
    int cnt = (int)countsf[k];

    float sum = 0.f;
    for (int r = base + w; r < base + cnt; r += 4) {
        int row = order[r];                       // wave-uniform
        sum += z[(size_t)row * DIM + d];          // coalesced 256B per row
    }

    __shared__ float s_red[256];
    s_red[threadIdx.x] = sum;
    __syncthreads();
    if (w == 0) {
        float tot = s_red[d] + s_red[64 + d] + s_red[128 + d] + s_red[192 + d];
        float nes = ema[k * DIM + d] * DECAYF + OMDF * tot;
        newema_out[k * DIM + d] = nes;
        newemb_out[k * DIM + d] = nes / cs_ws[k];
    }
}

__global__ __launch_bounds__(512) void finalize_kernel(const float* __restrict__ lossarr,
                                                       float* __restrict__ loss_out) {
    __shared__ float red[512];
    red[threadIdx.x] = lossarr[threadIdx.x];
    __syncthreads();
    for (int st = 256; st > 0; st >>= 1) {
        if (threadIdx.x < st) red[threadIdx.x] += red[threadIdx.x + st];
        __syncthreads();
    }
    if (threadIdx.x == 0)
        loss_out[0] = red[0] * (1.0f / ((float)N_PTS * (float)DIM));
}

extern "C" void kernel_launch(void* const* d_in, const int* in_sizes, int n_in,
                              void* d_out, int out_size, void* d_ws, size_t ws_size,
                              hipStream_t stream) {
    const float* z            = (const float*)d_in[0];
    const float* E            = (const float*)d_in[1];
    const float* cluster_size = (const float*)d_in[2];
    const float* ema          = (const float*)d_in[3];
    float* out = (float*)d_out;
    float* ws  = (float*)d_ws;

    hipMemsetAsync(ws + WS_COUNTS, 0, K_CODES * sizeof(float), stream);

    enorm_kernel<<<4, 256, 0, stream>>>(E, ws + WS_ENORM);

    argmin_kernel<<<N_PTS / 256, 256, 0, stream>>>(z, E, ws + WS_ENORM,
                                                   out + OUT_IDX,
                                                   ws + WS_COUNTS,
                                                   out + OUT_ZQ,
                                                   ws + WS_LOSSARR);

    scan_kernel<<<1, 1024, 0, stream>>>(cluster_size, ws + WS_COUNTS,
                                        out + OUT_NEWCS, ws + WS_CS,
                                        (int*)(ws + WS_START),
                                        (int*)(ws + WS_CURSOR));

    scatter_kernel<<<N_PTS / 256, 256, 0, stream>>>(out + OUT_IDX,
                                                    (int*)(ws + WS_CURSOR),
                                                    (int*)(ws + WS_ORDER));

    segsum_kernel<<<K_CODES, 256, 0, stream>>>(z, ema, ws + WS_COUNTS,
                                               (const int*)(ws + WS_START),
                                               (const int*)(ws + WS_ORDER),
                                               ws + WS_CS,
                                               out + OUT_NEWEMA,
                                               out + OUT_NEWEMB);

    finalize_kernel<<<1, 512, 0, stream>>>(ws + WS_LOSSARR, out + OUT_LOSS);
}

// Round 5
// 513.256 us; speedup vs baseline: 1.8460x; 1.8460x over previous
//
#include <hip/hip_runtime.h>

#define N_PTS 131072
#define K_CODES 1024
#define DIM 64
#define DECAYF 0.99f
#define OMDF 0.01f
#define EPSF 1e-5f
#define TAU 0.0625f

// ---- d_out layout (float elements, reference return order) ----
#define OUT_ZQ      0                  // [N, D]
#define OUT_LOSS    8388608            // scalar
#define OUT_IDX     8388609            // [N] (indices as floats)
#define OUT_NEWEMB  8519681            // [K, D]
#define OUT_NEWCS   8585217            // [K]
#define OUT_NEWEMA  8586241            // [K, D]

// ---- ws layout (float elements) ----
#define WS_C8       0                  // 8*K floats (memset 0)
#define WS_ACNT     8192               // 1 int (memset 0)
#define WS_ENORM    8208               // K
#define WS_CNT      9232               // K (summed counts)
#define WS_START    10256              // K ints
#define WS_CUR8     11280              // 8*K ints
#define WS_LOSSARR  19472              // 512
#define WS_CS       19984              // K
#define WS_AMBIG    21008              // N ints
#define WS_ORDER    152080             // N ints
#define WS_E2       283152             // K*128 bf16 (32768 float slots); byte off %16==0

typedef __attribute__((ext_vector_type(8))) short bf16x8;
typedef __attribute__((ext_vector_type(4))) float f32x4;

static __device__ inline short f2bf(float f) {
    unsigned u = __float_as_uint(f);
    unsigned r = (u + 0x7fffu + ((u >> 16) & 1u)) >> 16;   // RNE
    return (short)r;
}
static __device__ inline float bf2f(short h) {
    return __uint_as_float(((unsigned)(unsigned short)h) << 16);
}

// E -> E2 = bf16 hi/lo split of (-2E), K-layout [hi(64) | lo(64)]; enorm fp32.
__global__ __launch_bounds__(256) void econv_kernel(const float* __restrict__ E,
                                                    short* __restrict__ E2,
                                                    float* __restrict__ enorm) {
    int k = blockIdx.x * 256 + threadIdx.x;
    const float* ep = E + (size_t)k * DIM;
    short* o = E2 + (size_t)k * 128;
    float s = 0.f;
#pragma unroll
    for (int d = 0; d < 64; ++d) {
        float f = ep[d];
        s += f * f;
        float m = -2.f * f;
        short h = f2bf(m);
        o[d] = h;
        o[64 + d] = f2bf(m - bf2f(h));
    }
    enorm[k] = s;
}

// 512 blocks x 256 thr; wave handles 64 rows (4 m-tiles), sweeps all 1024
// codes as 64 n-tiles of a split bf16 GEMM. 3-product Ootomo split:
//   score_dot = zh.eh + zh.el + zl.eh   (drops only the ~2^-18 zl.el term)
// => 6 MFMAs (K=32) per m-tile per n-tile. Online top-2 per row in C-layout,
// 16-lane butterfly merge. Rows with top-2 gap < TAU -> exact fp32 rescue.
__global__ __launch_bounds__(256) void argmin_mfma(const float* __restrict__ z,
                                                   const short* __restrict__ E2,
                                                   const float* __restrict__ enorm,
                                                   float* __restrict__ out_idx_f,
                                                   float* __restrict__ counts8,
                                                   int* __restrict__ ambig_cnt,
                                                   int* __restrict__ ambig) {
    int tid = threadIdx.x;
    int w = tid >> 6, lane = tid & 63;
    int c = lane & 15, q = lane >> 4;
    int mbase = blockIdx.x * 256 + w * 64;

    // A-frags, hi/lo split. A[m=lane&15][k=q*8+j].
    // index [t][p]: p = 0: hi d0-31, 1: hi d32-63, 2: lo d0-31, 3: lo d32-63
    bf16x8 a[4][4];
#pragma unroll
    for (int t = 0; t < 4; ++t) {
        const float* zp = z + (size_t)(mbase + t * 16 + c) * DIM;
        const float4* z4a = (const float4*)(zp + q * 8);
        const float4* z4b = (const float4*)(zp + 32 + q * 8);
        float f[16];
        float4 v0 = z4a[0], v1 = z4a[1], v2 = z4b[0], v3 = z4b[1];
        f[0]=v0.x; f[1]=v0.y; f[2]=v0.z; f[3]=v0.w;
        f[4]=v1.x; f[5]=v1.y; f[6]=v1.z; f[7]=v1.w;
        f[8]=v2.x; f[9]=v2.y; f[10]=v2.z; f[11]=v2.w;
        f[12]=v3.x; f[13]=v3.y; f[14]=v3.z; f[15]=v3.w;
#pragma unroll
        for (int j = 0; j < 8; ++j) {
            short h0 = f2bf(f[j]);
            a[t][0][j] = h0;
            a[t][2][j] = f2bf(f[j] - bf2f(h0));
            short h1 = f2bf(f[8 + j]);
            a[t][1][j] = h1;
            a[t][3][j] = f2bf(f[8 + j] - bf2f(h1));
        }
    }

    float s1[16], s2[16];
    int i1[16];
#pragma unroll
    for (int idx = 0; idx < 16; ++idx) { s1[idx] = INFINITY; s2[idx] = INFINITY; i1[idx] = 0; }

    int vcode = c;
    for (int tile = 0; tile < 64; ++tile) {
        // B-frags: B[n=lane&15][k=q*8+j] from E2 row (tile*16+c), 16B loads
        const bf16x8* bp = (const bf16x8*)E2 + ((size_t)(tile * 16 + c) * 16) + q;
        bf16x8 bh0 = bp[0], bh1 = bp[4], bl0 = bp[8], bl1 = bp[12];
        float en = enorm[tile * 16 + c];
#pragma unroll
        for (int t = 0; t < 4; ++t) {
            f32x4 acc = {0.f, 0.f, 0.f, 0.f};
            // cross terms first, hi*hi last
            acc = __builtin_amdgcn_mfma_f32_16x16x32_bf16(a[t][0], bl0, acc, 0, 0, 0); // zh.el
            acc = __builtin_amdgcn_mfma_f32_16x16x32_bf16(a[t][1], bl1, acc, 0, 0, 0);
            acc = __builtin_amdgcn_mfma_f32_16x16x32_bf16(a[t][2], bh0, acc, 0, 0, 0); // zl.eh
            acc = __builtin_amdgcn_mfma_f32_16x16x32_bf16(a[t][3], bh1, acc, 0, 0, 0);
            acc = __builtin_amdgcn_mfma_f32_16x16x32_bf16(a[t][0], bh0, acc, 0, 0, 0); // zh.eh
            acc = __builtin_amdgcn_mfma_f32_16x16x32_bf16(a[t][1], bh1, acc, 0, 0, 0);
#pragma unroll
            for (int i = 0; i < 4; ++i) {
                float s = en + acc[i];        // enorm - 2 z.e
                int idx = t * 4 + i;
                bool bl = s < s1[idx];
                s2[idx] = bl ? s1[idx] : fminf(s2[idx], s);
                i1[idx] = bl ? vcode : i1[idx];
                s1[idx] = bl ? s : s1[idx];
            }
        }
        vcode += 16;
    }

    // merge the 16 col-lanes (same rows) per quad
#pragma unroll
    for (int off = 1; off < 16; off <<= 1) {
#pragma unroll
        for (int idx = 0; idx < 16; ++idx) {
            float os1 = __shfl_xor(s1[idx], off);
            float os2 = __shfl_xor(s2[idx], off);
            int   oi1 = __shfl_xor(i1[idx], off);
            float ns2 = fminf(fmaxf(s1[idx], os1), fminf(s2[idx], os2));
            if (os1 < s1[idx]) { s1[idx] = os1; i1[idx] = oi1; }
            s2[idx] = ns2;
        }
    }

    if (c == 0) {
#pragma unroll
        for (int idx = 0; idx < 16; ++idx) {
            int t = idx >> 2, i = idx & 3;
            int row = mbase + t * 16 + q * 4 + i;
            int code = i1[idx];
            out_idx_f[row] = (float)code;
            if (s2[idx] - s1[idx] >= TAU) {
                atomicAdd(&counts8[(((unsigned)row >> 8) & 7) * K_CODES + code], 1.0f);
            } else {
                int p = atomicAdd(ambig_cnt, 1);
                ambig[p] = row;
            }
        }
    }
}

// Wave per ambiguous row: exact fp32 rescore over all K codes.
__global__ __launch_bounds__(256) void rescue_kernel(const float* __restrict__ z,
                                                     const float* __restrict__ E,
                                                     const float* __restrict__ enorm,
                                                     const int* __restrict__ ambig_cnt,
                                                     const int* __restrict__ ambig,
                                                     float* __restrict__ out_idx_f,
                                                     float* __restrict__ counts8) {
    int lane = threadIdx.x & 63;
    int wave = (blockIdx.x * 256 + threadIdx.x) >> 6;
    int nw = gridDim.x * 4;
    int cnt = *ambig_cnt;
    for (int a = wave; a < cnt; a += nw) {
        int row = ambig[a];
        const float4* zp = (const float4*)(z + (size_t)row * DIM);
        float4 zr[16];
#pragma unroll
        for (int i = 0; i < 16; ++i) zr[i] = zp[i];
        float best = INFINITY;
        int bi = 0;
        for (int j = 0; j < 16; ++j) {
            int code = j * 64 + lane;
            const float4* ep = (const float4*)(E + (size_t)code * DIM);
            float d0 = 0.f, d1 = 0.f, d2 = 0.f, d3 = 0.f;
#pragma unroll
            for (int i = 0; i < 16; ++i) {
                float4 ev = ep[i];
                d0 += zr[i].x * ev.x; d1 += zr[i].y * ev.y;
                d2 += zr[i].z * ev.z; d3 += zr[i].w * ev.w;
            }
            float s = enorm[code] - 2.f * ((d0 + d1) + (d2 + d3));
            if (s < best) { best = s; bi = code; }
        }
#pragma unroll
        for (int off = 1; off < 64; off <<= 1) {
            float ob = __shfl_xor(best, off);
            int oi = __shfl_xor(bi, off);
            if (ob < best || (ob == best && oi < bi)) { best = ob; bi = oi; }
        }
        if (lane == 0) {
            out_idx_f[row] = (float)bi;
            atomicAdd(&counts8[(((unsigned)row >> 8) & 7) * K_CODES + bi], 1.0f);
        }
    }
}

// Exact z_q gather-write + commitment loss (after rescue fixed the indices).
__global__ __launch_bounds__(256) void zq_loss_kernel(const float* __restrict__ z,
                                                      const float* __restrict__ E,
                                                      const float* __restrict__ idx_f,
                                                      float* __restrict__ zq,
                                                      float* __restrict__ lossarr) {
    __shared__ int s_k[256];
    __shared__ float red[256];
    int tid = threadIdx.x;
    int rbase = blockIdx.x * 256;
    s_k[tid] = (int)idx_f[rbase + tid];
    __syncthreads();
    float acc = 0.f;
    size_t ebase = (size_t)rbase * DIM;
    for (int it = 0; it < 64; ++it) {
        int le = it * 256 + tid;
        int rl = le >> 6, d = le & 63;
        float ev = E[(size_t)s_k[rl] * DIM + d];
        float zv = z[ebase + le];
        zq[ebase + le] = ev;
        float df = zv - ev;
        acc += df * df;
    }
    red[tid] = acc;
    __syncthreads();
    for (int st = 128; st > 0; st >>= 1) {
        if (tid < st) red[tid] += red[tid + st];
        __syncthreads();
    }
    if (tid == 0) lossarr[blockIdx.x] = red[0];
}

// counts8 -> cnt, ncs, n, cs, start (prefix), sharded cursors.
__global__ __launch_bounds__(1024) void scan_kernel(const float* __restrict__ cluster_size,
                                                    const float* __restrict__ counts8,
                                                    float* __restrict__ ncs_out,
                                                    float* __restrict__ cs_ws,
                                                    float* __restrict__ cnt_out,
                                                    int* __restrict__ start,
                                                    int* __restrict__ cursor8) {
    int k = threadIdx.x;
    float c8[8];
    float cnt = 0.f;
#pragma unroll
    for (int s = 0; s < 8; ++s) { c8[s] = counts8[s * K_CODES + k]; cnt += c8[s]; }
    cnt_out[k] = cnt;
    float ncs = cluster_size[k] * DECAYF + OMDF * cnt;
    ncs_out[k] = ncs;

    __shared__ float red[1024];
    __shared__ int pfx[1024];
    red[k] = ncs;
    pfx[k] = (int)cnt;
    __syncthreads();
    for (int st = 512; st > 0; st >>= 1) {
        if (k < st) red[k] += red[k + st];
        __syncthreads();
    }
    float n = red[0];
    cs_ws[k] = (ncs + EPSF) / (n + (float)K_CODES * EPSF) * n;

    int my = (int)cnt;
    for (int off = 1; off < 1024; off <<= 1) {
        int add = (k >= off) ? pfx[k - off] : 0;
        __syncthreads();
        pfx[k] += add;
        __syncthreads();
    }
    int excl = pfx[k] - my;
    start[k] = excl;
    int run = excl;
#pragma unroll
    for (int s = 0; s < 8; ++s) { cursor8[s * K_CODES + k] = run; run += (int)c8[s]; }
}

__global__ __launch_bounds__(256) void scatter_kernel(const float* __restrict__ idx_f,
                                                      int* __restrict__ cursor8,
                                                      int* __restrict__ order) {
    int row = blockIdx.x * 256 + threadIdx.x;
    int k = (int)idx_f[row];
    int shard = ((unsigned)row >> 8) & 7;
    int p = atomicAdd(&cursor8[shard * K_CODES + k], 1);
    order[p] = row;
}

// One block (4 waves) per code: segment-sum of z rows, fused EMA epilogue.
__global__ __launch_bounds__(256) void segsum_kernel(const float* __restrict__ z,
                                                     const float* __restrict__ ema,
                                                     const float* __restrict__ cntf,
                                                     const int* __restrict__ start,
                                                     const int* __restrict__ order,
                                                     const float* __restrict__ cs_ws,
                                                     float* __restrict__ newema_out,
                                                     float* __restrict__ newemb_out) {
    int k = blockIdx.x;
    int d = threadIdx.x & 63;
    int w = threadIdx.x >> 6;
    int base = start[k];
    int cnt = (int)cntf[k];

    float sum = 0.f;
    for (int r = base + w; r < base + cnt; r += 4) {
        int row = order[r];
        sum += z[(size_t)row * DIM + d];
    }

    __shared__ float s_red[256];
    s_red[threadIdx.x] = sum;
    __syncthreads();
    if (w == 0) {
        float tot = s_red[d] + s_red[64 + d] + s_red[128 + d] + s_red[192 + d];
        float nes = ema[k * DIM + d] * DECAYF + OMDF * tot;
        newema_out[k * DIM + d] = nes;
        newemb_out[k * DIM + d] = nes / cs_ws[k];
    }
}

__global__ __launch_bounds__(512) void finalize_kernel(const float* __restrict__ lossarr,
                                                       float* __restrict__ loss_out) {
    __shared__ float red[512];
    red[threadIdx.x] = lossarr[threadIdx.x];
    __syncthreads();
    for (int st = 256; st > 0; st >>= 1) {
        if (threadIdx.x < st) red[threadIdx.x] += red[threadIdx.x + st];
        __syncthreads();
    }
    if (threadIdx.x == 0)
        loss_out[0] = red[0] * (1.0f / ((float)N_PTS * (float)DIM));
}

extern "C" void kernel_launch(void* const* d_in, const int* in_sizes, int n_in,
                              void* d_out, int out_size, void* d_ws, size_t ws_size,
                              hipStream_t stream) {
    const float* z            = (const float*)d_in[0];
    const float* E            = (const float*)d_in[1];
    const float* cluster_size = (const float*)d_in[2];
    const float* ema          = (const float*)d_in[3];
    float* out = (float*)d_out;
    float* ws  = (float*)d_ws;

    // zero counts8 + ambig_cnt
    hipMemsetAsync(ws + WS_C8, 0, (8 * K_CODES + 16) * sizeof(float), stream);

    econv_kernel<<<4, 256, 0, stream>>>(E, (short*)(ws + WS_E2), ws + WS_ENORM);

    argmin_mfma<<<N_PTS / 256, 256, 0, stream>>>(z, (const short*)(ws + WS_E2),
                                                 ws + WS_ENORM,
                                                 out + OUT_IDX,
                                                 ws + WS_C8,
                                                 (int*)(ws + WS_ACNT),
                                                 (int*)(ws + WS_AMBIG));

    rescue_kernel<<<256, 256, 0, stream>>>(z, E, ws + WS_ENORM,
                                           (const int*)(ws + WS_ACNT),
                                           (const int*)(ws + WS_AMBIG),
                                           out + OUT_IDX,
                                           ws + WS_C8);

    zq_loss_kernel<<<N_PTS / 256, 256, 0, stream>>>(z, E, out + OUT_IDX,
                                                    out + OUT_ZQ,
                                                    ws + WS_LOSSARR);

    scan_kernel<<<1, 1024, 0, stream>>>(cluster_size, ws + WS_C8,
                                        out + OUT_NEWCS, ws + WS_CS,
                                        ws + WS_CNT,
                                        (int*)(ws + WS_START),
                                        (int*)(ws + WS_CUR8));

    scatter_kernel<<<N_PTS / 256, 256, 0, stream>>>(out + OUT_IDX,
                                                    (int*)(ws + WS_CUR8),
                                                    (int*)(ws + WS_ORDER));

    segsum_kernel<<<K_CODES, 256, 0, stream>>>(z, ema, ws + WS_CNT,
                                               (const int*)(ws + WS_START),
                                               (const int*)(ws + WS_ORDER),
                                               ws + WS_CS,
                                               out + OUT_NEWEMA,
                                               out + OUT_NEWEMB);

    finalize_kernel<<<1, 512, 0, stream>>>(ws + WS_LOSSARR, out + OUT_LOSS);
}

// Round 6
// 263.114 us; speedup vs baseline: 3.6009x; 1.9507x over previous
//
#include <hip/hip_runtime.h>

#define N_PTS 131072
#define K_CODES 1024
#define DIM 64
#define DECAYF 0.99f
#define OMDF 0.01f
#define EPSF 1e-5f
#define TAU 0.0625f

// ---- d_out layout (float elements, reference return order) ----
#define OUT_ZQ      0                  // [N, D]
#define OUT_LOSS    8388608            // scalar
#define OUT_IDX     8388609            // [N] (indices as floats)
#define OUT_NEWEMB  8519681            // [K, D]
#define OUT_NEWCS   8585217            // [K]
#define OUT_NEWEMA  8586241            // [K, D]

// ---- ws layout (float elements) ----
// zero region: [0, WS_ZERO_END)
#define WS_C8       0                  // 8*K floats
#define WS_ACNT     8192               // 16 ints
#define WS_EMBSUM   8208               // K*D floats (atomic accumulator)
#define WS_ZERO_END 73744
#define WS_ENORM    73744              // K
#define WS_CNT      74768              // K
#define WS_START    75792              // K ints
#define WS_CUR8     76816              // 8*K ints
#define WS_LOSSARR  85008              // 512
#define WS_CS       85520              // K
#define WS_AMBIG    86544              // N ints
#define WS_ORDER    217616             // N ints (packed code<<17|row)
#define WS_E2       348688             // K*128 bf16 (32768 float slots); byte off %16==0

typedef __attribute__((ext_vector_type(8))) short bf16x8;
typedef __attribute__((ext_vector_type(4))) float f32x4;

static __device__ inline short f2bf(float f) {
    unsigned u = __float_as_uint(f);
    unsigned r = (u + 0x7fffu + ((u >> 16) & 1u)) >> 16;   // RNE
    return (short)r;
}
static __device__ inline float bf2f(short h) {
    return __uint_as_float(((unsigned)(unsigned short)h) << 16);
}

// E -> E2 = bf16 hi/lo split of (-2E), K-layout [hi(64) | lo(64)]; enorm fp32.
__global__ __launch_bounds__(256) void econv_kernel(const float* __restrict__ E,
                                                    short* __restrict__ E2,
                                                    float* __restrict__ enorm) {
    int k = blockIdx.x * 256 + threadIdx.x;
    const float* ep = E + (size_t)k * DIM;
    short* o = E2 + (size_t)k * 128;
    float s = 0.f;
#pragma unroll
    for (int d = 0; d < 64; ++d) {
        float f = ep[d];
        s += f * f;
        float m = -2.f * f;
        short h = f2bf(m);
        o[d] = h;
        o[64 + d] = f2bf(m - bf2f(h));
    }
    enorm[k] = s;
}

// 512 blocks x 256 thr; wave handles 64 rows (4 m-tiles), sweeps all 1024
// codes as 64 n-tiles of a split bf16 GEMM. 3-product Ootomo split:
//   score_dot = zh.eh + zh.el + zl.eh   (drops only the ~2^-18 zl.el term)
// Online top-2 per row in C-layout, 16-lane butterfly merge. Rows with
// top-2 gap < TAU -> exact fp32 rescue.
__global__ __launch_bounds__(256) void argmin_mfma(const float* __restrict__ z,
                                                   const short* __restrict__ E2,
                                                   const float* __restrict__ enorm,
                                                   float* __restrict__ out_idx_f,
                                                   float* __restrict__ counts8,
                                                   int* __restrict__ ambig_cnt,
                                                   int* __restrict__ ambig) {
    int tid = threadIdx.x;
    int w = tid >> 6, lane = tid & 63;
    int c = lane & 15, q = lane >> 4;
    int mbase = blockIdx.x * 256 + w * 64;

    // A-frags, hi/lo split. A[m=lane&15][k=q*8+j].
    bf16x8 a[4][4];   // [t][p]: p= 0:hi d0-31, 1:hi d32-63, 2:lo d0-31, 3:lo d32-63
#pragma unroll
    for (int t = 0; t < 4; ++t) {
        const float* zp = z + (size_t)(mbase + t * 16 + c) * DIM;
        const float4* z4a = (const float4*)(zp + q * 8);
        const float4* z4b = (const float4*)(zp + 32 + q * 8);
        float f[16];
        float4 v0 = z4a[0], v1 = z4a[1], v2 = z4b[0], v3 = z4b[1];
        f[0]=v0.x; f[1]=v0.y; f[2]=v0.z; f[3]=v0.w;
        f[4]=v1.x; f[5]=v1.y; f[6]=v1.z; f[7]=v1.w;
        f[8]=v2.x; f[9]=v2.y; f[10]=v2.z; f[11]=v2.w;
        f[12]=v3.x; f[13]=v3.y; f[14]=v3.z; f[15]=v3.w;
#pragma unroll
        for (int j = 0; j < 8; ++j) {
            short h0 = f2bf(f[j]);
            a[t][0][j] = h0;
            a[t][2][j] = f2bf(f[j] - bf2f(h0));
            short h1 = f2bf(f[8 + j]);
            a[t][1][j] = h1;
            a[t][3][j] = f2bf(f[8 + j] - bf2f(h1));
        }
    }

    float s1[16], s2[16];
    int i1[16];
#pragma unroll
    for (int idx = 0; idx < 16; ++idx) { s1[idx] = INFINITY; s2[idx] = INFINITY; i1[idx] = 0; }

    int vcode = c;
    for (int tile = 0; tile < 64; ++tile) {
        const bf16x8* bp = (const bf16x8*)E2 + ((size_t)(tile * 16 + c) * 16) + q;
        bf16x8 bh0 = bp[0], bh1 = bp[4], bl0 = bp[8], bl1 = bp[12];
        float en = enorm[tile * 16 + c];
#pragma unroll
        for (int t = 0; t < 4; ++t) {
            f32x4 acc = {0.f, 0.f, 0.f, 0.f};
            acc = __builtin_amdgcn_mfma_f32_16x16x32_bf16(a[t][0], bl0, acc, 0, 0, 0); // zh.el
            acc = __builtin_amdgcn_mfma_f32_16x16x32_bf16(a[t][1], bl1, acc, 0, 0, 0);
            acc = __builtin_amdgcn_mfma_f32_16x16x32_bf16(a[t][2], bh0, acc, 0, 0, 0); // zl.eh
            acc = __builtin_amdgcn_mfma_f32_16x16x32_bf16(a[t][3], bh1, acc, 0, 0, 0);
            acc = __builtin_amdgcn_mfma_f32_16x16x32_bf16(a[t][0], bh0, acc, 0, 0, 0); // zh.eh
            acc = __builtin_amdgcn_mfma_f32_16x16x32_bf16(a[t][1], bh1, acc, 0, 0, 0);
#pragma unroll
            for (int i = 0; i < 4; ++i) {
                float s = en + acc[i];
                int idx = t * 4 + i;
                bool bl = s < s1[idx];
                s2[idx] = bl ? s1[idx] : fminf(s2[idx], s);
                i1[idx] = bl ? vcode : i1[idx];
                s1[idx] = bl ? s : s1[idx];
            }
        }
        vcode += 16;
    }

#pragma unroll
    for (int off = 1; off < 16; off <<= 1) {
#pragma unroll
        for (int idx = 0; idx < 16; ++idx) {
            float os1 = __shfl_xor(s1[idx], off);
            float os2 = __shfl_xor(s2[idx], off);
            int   oi1 = __shfl_xor(i1[idx], off);
            float ns2 = fminf(fmaxf(s1[idx], os1), fminf(s2[idx], os2));
            if (os1 < s1[idx]) { s1[idx] = os1; i1[idx] = oi1; }
            s2[idx] = ns2;
        }
    }

    if (c == 0) {
#pragma unroll
        for (int idx = 0; idx < 16; ++idx) {
            int t = idx >> 2, i = idx & 3;
            int row = mbase + t * 16 + q * 4 + i;
            int code = i1[idx];
            out_idx_f[row] = (float)code;
            if (s2[idx] - s1[idx] >= TAU) {
                atomicAdd(&counts8[(((unsigned)row >> 8) & 7) * K_CODES + code], 1.0f);
            } else {
                int p = atomicAdd(ambig_cnt, 1);
                ambig[p] = row;
            }
        }
    }
}

// Wave per 2 ambiguous rows: exact fp32 rescore over all K codes, sharing
// each E element across both rows (halves L2 E-traffic vs 1 row/pass).
__global__ __launch_bounds__(256) void rescue_kernel(const float* __restrict__ z,
                                                     const float* __restrict__ E,
                                                     const float* __restrict__ enorm,
                                                     const int* __restrict__ ambig_cnt,
                                                     const int* __restrict__ ambig,
                                                     float* __restrict__ out_idx_f,
                                                     float* __restrict__ counts8) {
    int lane = threadIdx.x & 63;
    int wave = (blockIdx.x * 256 + threadIdx.x) >> 6;
    int nw = gridDim.x * 4;
    int cnt = *ambig_cnt;
    for (int a = 2 * wave; a < cnt; a += 2 * nw) {
        int row0 = ambig[a];
        bool two = (a + 1) < cnt;
        int row1 = two ? ambig[a + 1] : row0;
        const float4* zp0 = (const float4*)(z + (size_t)row0 * DIM);
        const float4* zp1 = (const float4*)(z + (size_t)row1 * DIM);
        float4 zr0[16], zr1[16];
#pragma unroll
        for (int i = 0; i < 16; ++i) { zr0[i] = zp0[i]; zr1[i] = zp1[i]; }
        float best0 = INFINITY, best1 = INFINITY;
        int bi0 = 0, bi1 = 0;
        for (int j = 0; j < 16; ++j) {
            int code = j * 64 + lane;
            const float4* ep = (const float4*)(E + (size_t)code * DIM);
            float a0 = 0.f, a1 = 0.f, a2 = 0.f, a3 = 0.f;
            float c0 = 0.f, c1 = 0.f, c2 = 0.f, c3 = 0.f;
#pragma unroll
            for (int i = 0; i < 16; ++i) {
                float4 ev = ep[i];
                a0 += zr0[i].x * ev.x; a1 += zr0[i].y * ev.y;
                a2 += zr0[i].z * ev.z; a3 += zr0[i].w * ev.w;
                c0 += zr1[i].x * ev.x; c1 += zr1[i].y * ev.y;
                c2 += zr1[i].z * ev.z; c3 += zr1[i].w * ev.w;
            }
            float en = enorm[code];
            float s0 = en - 2.f * ((a0 + a1) + (a2 + a3));
            float s1 = en - 2.f * ((c0 + c1) + (c2 + c3));
            if (s0 < best0) { best0 = s0; bi0 = code; }
            if (s1 < best1) { best1 = s1; bi1 = code; }
        }
#pragma unroll
        for (int off = 1; off < 64; off <<= 1) {
            float ob = __shfl_xor(best0, off);
            int oi = __shfl_xor(bi0, off);
            if (ob < best0 || (ob == best0 && oi < bi0)) { best0 = ob; bi0 = oi; }
            float ob1 = __shfl_xor(best1, off);
            int oi1 = __shfl_xor(bi1, off);
            if (ob1 < best1 || (ob1 == best1 && oi1 < bi1)) { best1 = ob1; bi1 = oi1; }
        }
        if (lane == 0) {
            out_idx_f[row0] = (float)bi0;
            atomicAdd(&counts8[(((unsigned)row0 >> 8) & 7) * K_CODES + bi0], 1.0f);
            if (two) {
                out_idx_f[row1] = (float)bi1;
                atomicAdd(&counts8[(((unsigned)row1 >> 8) & 7) * K_CODES + bi1], 1.0f);
            }
        }
    }
}

// Exact z_q gather-write + commitment loss (after rescue fixed the indices).
__global__ __launch_bounds__(256) void zq_loss_kernel(const float* __restrict__ z,
                                                      const float* __restrict__ E,
                                                      const float* __restrict__ idx_f,
                                                      float* __restrict__ zq,
                                                      float* __restrict__ lossarr) {
    __shared__ int s_k[256];
    __shared__ float red[256];
    int tid = threadIdx.x;
    int rbase = blockIdx.x * 256;
    s_k[tid] = (int)idx_f[rbase + tid];
    __syncthreads();
    float acc = 0.f;
    size_t ebase = (size_t)rbase * DIM;
    for (int it = 0; it < 64; ++it) {
        int le = it * 256 + tid;
        int rl = le >> 6, d = le & 63;
        float ev = E[(size_t)s_k[rl] * DIM + d];
        float zv = z[ebase + le];
        zq[ebase + le] = ev;
        float df = zv - ev;
        acc += df * df;
    }
    red[tid] = acc;
    __syncthreads();
    for (int st = 128; st > 0; st >>= 1) {
        if (tid < st) red[tid] += red[tid + st];
        __syncthreads();
    }
    if (tid == 0) lossarr[blockIdx.x] = red[0];
}

// counts8 -> cnt, ncs, n, cs, sharded cursors for the counting sort.
__global__ __launch_bounds__(1024) void scan_kernel(const float* __restrict__ cluster_size,
                                                    const float* __restrict__ counts8,
                                                    float* __restrict__ ncs_out,
                                                    float* __restrict__ cs_ws,
                                                    float* __restrict__ cnt_out,
                                                    int* __restrict__ start,
                                                    int* __restrict__ cursor8) {
    int k = threadIdx.x;
    float c8[8];
    float cnt = 0.f;
#pragma unroll
    for (int s = 0; s < 8; ++s) { c8[s] = counts8[s * K_CODES + k]; cnt += c8[s]; }
    cnt_out[k] = cnt;
    float ncs = cluster_size[k] * DECAYF + OMDF * cnt;
    ncs_out[k] = ncs;

    __shared__ float red[1024];
    __shared__ int pfx[1024];
    red[k] = ncs;
    pfx[k] = (int)cnt;
    __syncthreads();
    for (int st = 512; st > 0; st >>= 1) {
        if (k < st) red[k] += red[k + st];
        __syncthreads();
    }
    float n = red[0];
    cs_ws[k] = (ncs + EPSF) / (n + (float)K_CODES * EPSF) * n;

    int my = (int)cnt;
    for (int off = 1; off < 1024; off <<= 1) {
        int add = (k >= off) ? pfx[k - off] : 0;
        __syncthreads();
        pfx[k] += add;
        __syncthreads();
    }
    int excl = pfx[k] - my;
    start[k] = excl;
    int run = excl;
#pragma unroll
    for (int s = 0; s < 8; ++s) { cursor8[s * K_CODES + k] = run; run += (int)c8[s]; }
}

// order[p] = code<<17 | row  (code<1024, row<2^17)
__global__ __launch_bounds__(256) void scatter_kernel(const float* __restrict__ idx_f,
                                                      int* __restrict__ cursor8,
                                                      int* __restrict__ order) {
    int row = blockIdx.x * 256 + threadIdx.x;
    int k = (int)idx_f[row];
    int shard = ((unsigned)row >> 8) & 7;
    int p = atomicAdd(&cursor8[shard * K_CODES + k], 1);
    order[p] = (k << 17) | row;
}

// Work-partitioned segment sum: each wave owns a fixed 64-entry slice of the
// sorted order array (perfect load balance); lane = dim. Run-length
// accumulate in registers, flush once per code-run with a 64-lane atomicAdd.
__global__ __launch_bounds__(256) void segsum_kernel(const float* __restrict__ z,
                                                     const int* __restrict__ order,
                                                     float* __restrict__ embsum) {
    int lane = threadIdx.x & 63;
    int w = threadIdx.x >> 6;
    int wave = blockIdx.x * 4 + w;
    int base = wave * 64;

    int my = order[base + lane];    // one packed entry per lane, coalesced

    int cur = __shfl(my, 0, 64) >> 17;
    float sum = 0.f;
#pragma unroll 8
    for (int i = 0; i < 64; ++i) {
        int p = __shfl(my, i, 64);
        int row = p & 0x1FFFF;
        int code = p >> 17;
        float v = z[(size_t)row * DIM + lane];   // coalesced 256B
        if (code != cur) {                        // wave-uniform branch
            atomicAdd(&embsum[(size_t)cur * DIM + lane], sum);
            sum = 0.f;
            cur = code;
        }
        sum += v;
    }
    atomicAdd(&embsum[(size_t)cur * DIM + lane], sum);
}

// EMA epilogue over [K, D].
__global__ __launch_bounds__(256) void ema2_kernel(const float* __restrict__ ema,
                                                   const float* __restrict__ embsum,
                                                   const float* __restrict__ cs_ws,
                                                   float* __restrict__ newema_out,
                                                   float* __restrict__ newemb_out) {
    int i = blockIdx.x * 256 + threadIdx.x;
    float nes = ema[i] * DECAYF + OMDF * embsum[i];
    newema_out[i] = nes;
    newemb_out[i] = nes / cs_ws[i >> 6];
}

__global__ __launch_bounds__(512) void finalize_kernel(const float* __restrict__ lossarr,
                                                       float* __restrict__ loss_out) {
    __shared__ float red[512];
    red[threadIdx.x] = lossarr[threadIdx.x];
    __syncthreads();
    for (int st = 256; st > 0; st >>= 1) {
        if (threadIdx.x < st) red[threadIdx.x] += red[threadIdx.x + st];
        __syncthreads();
    }
    if (threadIdx.x == 0)
        loss_out[0] = red[0] * (1.0f / ((float)N_PTS * (float)DIM));
}

extern "C" void kernel_launch(void* const* d_in, const int* in_sizes, int n_in,
                              void* d_out, int out_size, void* d_ws, size_t ws_size,
                              hipStream_t stream) {
    const float* z            = (const float*)d_in[0];
    const float* E            = (const float*)d_in[1];
    const float* cluster_size = (const float*)d_in[2];
    const float* ema          = (const float*)d_in[3];
    float* out = (float*)d_out;
    float* ws  = (float*)d_ws;

    // zero counts8 + ambig_cnt + embsum accumulator
    hipMemsetAsync(ws, 0, (size_t)WS_ZERO_END * sizeof(float), stream);

    econv_kernel<<<4, 256, 0, stream>>>(E, (short*)(ws + WS_E2), ws + WS_ENORM);

    argmin_mfma<<<N_PTS / 256, 256, 0, stream>>>(z, (const short*)(ws + WS_E2),
                                                 ws + WS_ENORM,
                                                 out + OUT_IDX,
                                                 ws + WS_C8,
                                                 (int*)(ws + WS_ACNT),
                                                 (int*)(ws + WS_AMBIG));

    rescue_kernel<<<512, 256, 0, stream>>>(z, E, ws + WS_ENORM,
                                           (const int*)(ws + WS_ACNT),
                                           (const int*)(ws + WS_AMBIG),
                                           out + OUT_IDX,
                                           ws + WS_C8);

    zq_loss_kernel<<<N_PTS / 256, 256, 0, stream>>>(z, E, out + OUT_IDX,
                                                    out + OUT_ZQ,
                                                    ws + WS_LOSSARR);

    scan_kernel<<<1, 1024, 0, stream>>>(cluster_size, ws + WS_C8,
                                        out + OUT_NEWCS, ws + WS_CS,
                                        ws + WS_CNT,
                                        (int*)(ws + WS_START),
                                        (int*)(ws + WS_CUR8));

    scatter_kernel<<<N_PTS / 256, 256, 0, stream>>>(out + OUT_IDX,
                                                    (int*)(ws + WS_CUR8),
                                                    (int*)(ws + WS_ORDER));

    segsum_kernel<<<N_PTS / 256, 256, 0, stream>>>(z,
                                                   (const int*)(ws + WS_ORDER),
                                                   ws + WS_EMBSUM);

    ema2_kernel<<<K_CODES * DIM / 256, 256, 0, stream>>>(ema, ws + WS_EMBSUM,
                                                         ws + WS_CS,
                                                         out + OUT_NEWEMA,
                                                         out + OUT_NEWEMB);

    finalize_kernel<<<1, 512, 0, stream>>>(ws + WS_LOSSARR, out + OUT_LOSS);
}

// Round 7
// 249.043 us; speedup vs baseline: 3.8043x; 1.0565x over previous
//
#include <hip/hip_runtime.h>

#define N_PTS 131072
#define K_CODES 1024
#define DIM 64
#define DECAYF 0.99f
#define OMDF 0.01f
#define EPSF 1e-5f

// ---- d_out layout (float elements, reference return order) ----
#define OUT_ZQ      0                  // [N, D]
#define OUT_LOSS    8388608            // scalar
#define OUT_IDX     8388609            // [N] (indices as floats)
#define OUT_NEWEMB  8519681            // [K, D]
#define OUT_NEWCS   8585217            // [K]
#define OUT_NEWEMA  8586241            // [K, D]

// ---- ws layout (float elements) ----
// zero region: [0, WS_ZERO_END)
#define WS_C8       0                  // 8*K floats
#define WS_ACNT     8192               // 16 ints
#define WS_LOSS     8208               // 16 floats
#define WS_EMBSUM   8224               // K*D floats (atomic accumulator)
#define WS_ZERO_END 73760
#define WS_ENORM    73760              // K
#define WS_CUR8     74784              // 8*K ints
#define WS_CS       82976              // K
#define WS_AMBIG    84000              // N ints
#define WS_ORDER    215072             // N ints (packed code<<17|row)
#define WS_E2       346144             // K*128 bf16 (32768 float slots); byte off %16==0

typedef __attribute__((ext_vector_type(8))) short bf16x8;
typedef __attribute__((ext_vector_type(4))) float f32x4;

static __device__ inline short f2bf(float f) {
    unsigned u = __float_as_uint(f);
    unsigned r = (u + 0x7fffu + ((u >> 16) & 1u)) >> 16;   // RNE
    return (short)r;
}
static __device__ inline float bf2f(short h) {
    return __uint_as_float(((unsigned)(unsigned short)h) << 16);
}

// E -> E2 = bf16 hi/lo split of (-2E), K-layout [hi(64) | lo(64)]; enorm fp32.
__global__ __launch_bounds__(256) void econv_kernel(const float* __restrict__ E,
                                                    short* __restrict__ E2,
                                                    float* __restrict__ enorm) {
    int k = blockIdx.x * 256 + threadIdx.x;
    const float* ep = E + (size_t)k * DIM;
    short* o = E2 + (size_t)k * 128;
    float s = 0.f;
#pragma unroll
    for (int d = 0; d < 64; ++d) {
        float f = ep[d];
        s += f * f;
        float m = -2.f * f;
        short h = f2bf(m);
        o[d] = h;
        o[64 + d] = f2bf(m - bf2f(h));
    }
    enorm[k] = s;
}

// 512 blocks x 256 thr; wave = 64 rows (4 m-tiles) x all 1024 codes (64
// n-tiles). 3-product Ootomo split bf16 GEMM; enorm rides in the MFMA C
// operand (acc init = en). Top-2 is index-free: code packed into the low
// 10 mantissa bits of the score; s1 = min, s2 = fmed3. Rows whose top-2
// gap < dynamic tau (covers pack+split error) -> exact fp32 rescue.
// Also: commitment-loss partial (znorm + s1) for non-ambiguous rows.
__global__ __launch_bounds__(256) void argmin_mfma(const float* __restrict__ z,
                                                   const short* __restrict__ E2,
                                                   const float* __restrict__ enorm,
                                                   float* __restrict__ out_idx_f,
                                                   float* __restrict__ counts8,
                                                   int* __restrict__ ambig_cnt,
                                                   int* __restrict__ ambig,
                                                   float* __restrict__ loss_ws) {
    int tid = threadIdx.x;
    int w = tid >> 6, lane = tid & 63;
    int c = lane & 15, q = lane >> 4;
    int mbase = blockIdx.x * 256 + w * 64;

    // A-frags, hi/lo split. A[m=lane&15][k=q*8+j]. Also exact znorm per
    // loaded row (row = mbase + t*16 + c).
    bf16x8 a[4][4];   // [t][p]: p= 0:hi d0-31, 1:hi d32-63, 2:lo d0-31, 3:lo d32-63
    float znorm_t[4];
#pragma unroll
    for (int t = 0; t < 4; ++t) {
        const float* zp = z + (size_t)(mbase + t * 16 + c) * DIM;
        const float4* z4a = (const float4*)(zp + q * 8);
        const float4* z4b = (const float4*)(zp + 32 + q * 8);
        float f[16];
        float4 v0 = z4a[0], v1 = z4a[1], v2 = z4b[0], v3 = z4b[1];
        f[0]=v0.x; f[1]=v0.y; f[2]=v0.z; f[3]=v0.w;
        f[4]=v1.x; f[5]=v1.y; f[6]=v1.z; f[7]=v1.w;
        f[8]=v2.x; f[9]=v2.y; f[10]=v2.z; f[11]=v2.w;
        f[12]=v3.x; f[13]=v3.y; f[14]=v3.z; f[15]=v3.w;
        float zn = 0.f;
#pragma unroll
        for (int j = 0; j < 16; ++j) zn += f[j] * f[j];
        // each quad holds 16 of the row's 64 dims; sum across the 4 quads
#pragma unroll
        for (int off = 16; off < 64; off <<= 1) zn += __shfl_xor(zn, off);
        znorm_t[t] = zn;
#pragma unroll
        for (int j = 0; j < 8; ++j) {
            short h0 = f2bf(f[j]);
            a[t][0][j] = h0;
            a[t][2][j] = f2bf(f[j] - bf2f(h0));
            short h1 = f2bf(f[8 + j]);
            a[t][1][j] = h1;
            a[t][3][j] = f2bf(f[8 + j] - bf2f(h1));
        }
    }

    float s1[16], s2[16];
#pragma unroll
    for (int idx = 0; idx < 16; ++idx) { s1[idx] = INFINITY; s2[idx] = INFINITY; }

    unsigned vcode = (unsigned)c;
    for (int tile = 0; tile < 64; ++tile) {
        const bf16x8* bp = (const bf16x8*)E2 + ((size_t)(tile * 16 + c) * 16) + q;
        bf16x8 bh0 = bp[0], bh1 = bp[4], bl0 = bp[8], bl1 = bp[12];
        float en = enorm[tile * 16 + c];
#pragma unroll
        for (int t = 0; t < 4; ++t) {
            f32x4 acc = {en, en, en, en};
            acc = __builtin_amdgcn_mfma_f32_16x16x32_bf16(a[t][0], bl0, acc, 0, 0, 0); // zh.el
            acc = __builtin_amdgcn_mfma_f32_16x16x32_bf16(a[t][1], bl1, acc, 0, 0, 0);
            acc = __builtin_amdgcn_mfma_f32_16x16x32_bf16(a[t][2], bh0, acc, 0, 0, 0); // zl.eh
            acc = __builtin_amdgcn_mfma_f32_16x16x32_bf16(a[t][3], bh1, acc, 0, 0, 0);
            acc = __builtin_amdgcn_mfma_f32_16x16x32_bf16(a[t][0], bh0, acc, 0, 0, 0); // zh.eh
            acc = __builtin_amdgcn_mfma_f32_16x16x32_bf16(a[t][1], bh1, acc, 0, 0, 0);
#pragma unroll
            for (int i = 0; i < 4; ++i) {
                // pack code into low 10 bits (bfi pattern), then min/med3
                float sp = __uint_as_float(
                    (__float_as_uint(acc[i]) & 0xFFFFFC00u) | vcode);
                int idx = t * 4 + i;
                float ns2 = __builtin_amdgcn_fmed3f(s1[idx], s2[idx], sp);
                s1[idx] = fminf(s1[idx], sp);
                s2[idx] = ns2;
            }
        }
        vcode += 16;
    }

    // merge the 16 col-lanes per quad (packed values carry the index)
#pragma unroll
    for (int off = 1; off < 16; off <<= 1) {
#pragma unroll
        for (int idx = 0; idx < 16; ++idx) {
            float os1 = __shfl_xor(s1[idx], off);
            float os2 = __shfl_xor(s2[idx], off);
            float ns1 = fminf(s1[idx], os1);
            s2[idx] = fminf(fmaxf(s1[idx], os1), fminf(s2[idx], os2));
            s1[idx] = ns1;
        }
    }

    // znorm transport: lane (q*16 + r) holds znorm for row mbase + t*16 + r
    float znr[16];
#pragma unroll
    for (int t = 0; t < 4; ++t)
#pragma unroll
        for (int i = 0; i < 4; ++i)
            znr[t * 4 + i] = __shfl(znorm_t[t], (q << 4) | (q * 4 + i), 64);

    __shared__ float lred[16];
    float lsum = 0.f;
    if (c == 0) {
#pragma unroll
        for (int idx = 0; idx < 16; ++idx) {
            int t = idx >> 2, i = idx & 3;
            int row = mbase + t * 16 + q * 4 + i;
            unsigned b1 = __float_as_uint(s1[idx]);
            int code = (int)(b1 & 1023u);
            out_idx_f[row] = (float)code;
            float s1v = __uint_as_float(b1 & 0xFFFFFC00u);
            float gap = s2[idx] - s1[idx];
            float tau = 0.008f + 8e-4f * (fabsf(s1[idx]) + fabsf(s2[idx]));
            if (gap >= tau) {
                atomicAdd(&counts8[(((unsigned)row >> 8) & 7) * K_CODES + code], 1.0f);
                lsum += znr[idx] + s1v;
            } else {
                int p = atomicAdd(ambig_cnt, 1);
                ambig[p] = row;
            }
        }
        lred[w * 4 + q] = lsum;
    }
    __syncthreads();
    if (tid == 0) {
        float tot = 0.f;
#pragma unroll
        for (int i = 0; i < 16; ++i) tot += lred[i];
        atomicAdd(loss_ws, tot);
    }
}

// Wave per 2 ambiguous rows: exact fp32 rescore over all K codes; also adds
// the exact loss contribution for those rows.
__global__ __launch_bounds__(256) void rescue_kernel(const float* __restrict__ z,
                                                     const float* __restrict__ E,
                                                     const float* __restrict__ enorm,
                                                     const int* __restrict__ ambig_cnt,
                                                     const int* __restrict__ ambig,
                                                     float* __restrict__ out_idx_f,
                                                     float* __restrict__ counts8,
                                                     float* __restrict__ loss_ws) {
    int lane = threadIdx.x & 63;
    int wave = (blockIdx.x * 256 + threadIdx.x) >> 6;
    int nw = gridDim.x * 4;
    int cnt = *ambig_cnt;
    for (int a = 2 * wave; a < cnt; a += 2 * nw) {
        int row0 = ambig[a];
        bool two = (a + 1) < cnt;
        int row1 = two ? ambig[a + 1] : row0;
        const float4* zp0 = (const float4*)(z + (size_t)row0 * DIM);
        const float4* zp1 = (const float4*)(z + (size_t)row1 * DIM);
        float4 zr0[16], zr1[16];
        float zn0 = 0.f, zn1 = 0.f;
#pragma unroll
        for (int i = 0; i < 16; ++i) {
            float4 u = zp0[i], v = zp1[i];
            zr0[i] = u; zr1[i] = v;
            zn0 += u.x * u.x + u.y * u.y + u.z * u.z + u.w * u.w;
            zn1 += v.x * v.x + v.y * v.y + v.z * v.z + v.w * v.w;
        }
        float best0 = INFINITY, best1 = INFINITY;
        int bi0 = 0, bi1 = 0;
        for (int j = 0; j < 16; ++j) {
            int code = j * 64 + lane;
            const float4* ep = (const float4*)(E + (size_t)code * DIM);
            float a0 = 0.f, a1 = 0.f, a2 = 0.f, a3 = 0.f;
            float c0 = 0.f, c1 = 0.f, c2 = 0.f, c3 = 0.f;
#pragma unroll
            for (int i = 0; i < 16; ++i) {
                float4 ev = ep[i];
                a0 += zr0[i].x * ev.x; a1 += zr0[i].y * ev.y;
                a2 += zr0[i].z * ev.z; a3 += zr0[i].w * ev.w;
                c0 += zr1[i].x * ev.x; c1 += zr1[i].y * ev.y;
                c2 += zr1[i].z * ev.z; c3 += zr1[i].w * ev.w;
            }
            float en = enorm[code];
            float s0 = en - 2.f * ((a0 + a1) + (a2 + a3));
            float s1 = en - 2.f * ((c0 + c1) + (c2 + c3));
            if (s0 < best0) { best0 = s0; bi0 = code; }
            if (s1 < best1) { best1 = s1; bi1 = code; }
        }
#pragma unroll
        for (int off = 1; off < 64; off <<= 1) {
            float ob = __shfl_xor(best0, off);
            int oi = __shfl_xor(bi0, off);
            if (ob < best0 || (ob == best0 && oi < bi0)) { best0 = ob; bi0 = oi; }
            float ob1 = __shfl_xor(best1, off);
            int oi1 = __shfl_xor(bi1, off);
            if (ob1 < best1 || (ob1 == best1 && oi1 < bi1)) { best1 = ob1; bi1 = oi1; }
        }
        if (lane == 0) {
            out_idx_f[row0] = (float)bi0;
            atomicAdd(&counts8[(((unsigned)row0 >> 8) & 7) * K_CODES + bi0], 1.0f);
            float ladd = zn0 + best0;
            if (two) {
                out_idx_f[row1] = (float)bi1;
                atomicAdd(&counts8[(((unsigned)row1 >> 8) & 7) * K_CODES + bi1], 1.0f);
                ladd += zn1 + best1;
            }
            atomicAdd(loss_ws, ladd);
        }
    }
}

// Pure z_q gather-write (indices final after rescue). One wave = one row per
// iteration: coalesced 256B E read (L2-hot) + coalesced 256B store.
__global__ __launch_bounds__(256) void zq_write_kernel(const float* __restrict__ E,
                                                       const float* __restrict__ idx_f,
                                                       float* __restrict__ zq) {
    __shared__ int s_k[256];
    int tid = threadIdx.x;
    int rbase = blockIdx.x * 256;
    s_k[tid] = (int)idx_f[rbase + tid];
    __syncthreads();
    size_t ebase = (size_t)rbase * DIM;
#pragma unroll 4
    for (int it = 0; it < 64; ++it) {
        int le = it * 256 + tid;
        int rl = le >> 6, d = le & 63;
        zq[ebase + le] = E[(size_t)s_k[rl] * DIM + d];
    }
}

// counts8 -> ncs, n, cs, sharded cursors. Shfl-scan, 2 barriers.
__global__ __launch_bounds__(1024) void scan_kernel(const float* __restrict__ cluster_size,
                                                    const float* __restrict__ counts8,
                                                    float* __restrict__ ncs_out,
                                                    float* __restrict__ cs_ws,
                                                    int* __restrict__ cursor8) {
    int k = threadIdx.x;
    int lane = k & 63, wv = k >> 6;
    float c8[8];
    float cnt = 0.f;
#pragma unroll
    for (int s = 0; s < 8; ++s) { c8[s] = counts8[s * K_CODES + k]; cnt += c8[s]; }
    float ncs = cluster_size[k] * DECAYF + OMDF * cnt;
    ncs_out[k] = ncs;

    // wave-inclusive scan of int counts
    int v = (int)cnt;
    int vs = v;
#pragma unroll
    for (int off = 1; off < 64; off <<= 1) {
        int o = __shfl_up(vs, off, 64);
        if (lane >= off) vs += o;
    }
    // wave total of ncs (for n)
    float fs = ncs;
#pragma unroll
    for (int off = 1; off < 64; off <<= 1) fs += __shfl_xor(fs, off);

    __shared__ int wtot[16];
    __shared__ float ftot[16];
    __shared__ float nsh;
    if (lane == 63) wtot[wv] = vs;
    if (lane == 0) ftot[wv] = fs;
    __syncthreads();
    if (k == 0) {
        int run = 0; float fn = 0.f;
#pragma unroll
        for (int i = 0; i < 16; ++i) {
            int t = wtot[i]; wtot[i] = run; run += t;
            fn += ftot[i];
        }
        nsh = fn;
    }
    __syncthreads();
    float n = nsh;
    cs_ws[k] = (ncs + EPSF) / (n + (float)K_CODES * EPSF) * n;

    int excl = vs - v + wtot[wv];
    int run = excl;
#pragma unroll
    for (int s = 0; s < 8; ++s) { cursor8[s * K_CODES + k] = run; run += (int)c8[s]; }
}

// order[p] = code<<17 | row
__global__ __launch_bounds__(256) void scatter_kernel(const float* __restrict__ idx_f,
                                                      int* __restrict__ cursor8,
                                                      int* __restrict__ order) {
    int row = blockIdx.x * 256 + threadIdx.x;
    int k = (int)idx_f[row];
    int shard = ((unsigned)row >> 8) & 7;
    int p = atomicAdd(&cursor8[shard * K_CODES + k], 1);
    order[p] = (k << 17) | row;
}

// Work-partitioned segment sum: each wave owns 64 entries of the sorted
// order array; lane = dim; run-length accumulate, flush per code-run.
__global__ __launch_bounds__(256) void segsum_kernel(const float* __restrict__ z,
                                                     const int* __restrict__ order,
                                                     float* __restrict__ embsum) {
    int lane = threadIdx.x & 63;
    int w = threadIdx.x >> 6;
    int wave = blockIdx.x * 4 + w;
    int base = wave * 64;

    int my = order[base + lane];

    int cur = __shfl(my, 0, 64) >> 17;
    float sum = 0.f;
#pragma unroll 8
    for (int i = 0; i < 64; ++i) {
        int p = __shfl(my, i, 64);
        int row = p & 0x1FFFF;
        int code = p >> 17;
        float v = z[(size_t)row * DIM + lane];
        if (code != cur) {
            atomicAdd(&embsum[(size_t)cur * DIM + lane], sum);
            sum = 0.f;
            cur = code;
        }
        sum += v;
    }
    atomicAdd(&embsum[(size_t)cur * DIM + lane], sum);
}

// EMA epilogue over [K, D] + loss finalize (block 0).
__global__ __launch_bounds__(256) void ema2_kernel(const float* __restrict__ ema,
                                                   const float* __restrict__ embsum,
                                                   const float* __restrict__ cs_ws,
                                                   const float* __restrict__ loss_ws,
                                                   float* __restrict__ newema_out,
                                                   float* __restrict__ newemb_out,
                                                   float* __restrict__ loss_out) {
    int i = blockIdx.x * 256 + threadIdx.x;
    float nes = ema[i] * DECAYF + OMDF * embsum[i];
    newema_out[i] = nes;
    newemb_out[i] = nes / cs_ws[i >> 6];
    if (i == 0)
        loss_out[0] = loss_ws[0] * (1.0f / ((float)N_PTS * (float)DIM));
}

extern "C" void kernel_launch(void* const* d_in, const int* in_sizes, int n_in,
                              void* d_out, int out_size, void* d_ws, size_t ws_size,
                              hipStream_t stream) {
    const float* z            = (const float*)d_in[0];
    const float* E            = (const float*)d_in[1];
    const float* cluster_size = (const float*)d_in[2];
    const float* ema          = (const float*)d_in[3];
    float* out = (float*)d_out;
    float* ws  = (float*)d_ws;

    // zero counts8 + ambig_cnt + loss + embsum accumulator
    hipMemsetAsync(ws, 0, (size_t)WS_ZERO_END * sizeof(float), stream);

    econv_kernel<<<4, 256, 0, stream>>>(E, (short*)(ws + WS_E2), ws + WS_ENORM);

    argmin_mfma<<<N_PTS / 256, 256, 0, stream>>>(z, (const short*)(ws + WS_E2),
                                                 ws + WS_ENORM,
                                                 out + OUT_IDX,
                                                 ws + WS_C8,
                                                 (int*)(ws + WS_ACNT),
                                                 (int*)(ws + WS_AMBIG),
                                                 ws + WS_LOSS);

    rescue_kernel<<<512, 256, 0, stream>>>(z, E, ws + WS_ENORM,
                                           (const int*)(ws + WS_ACNT),
                                           (const int*)(ws + WS_AMBIG),
                                           out + OUT_IDX,
                                           ws + WS_C8,
                                           ws + WS_LOSS);

    zq_write_kernel<<<N_PTS / 256, 256, 0, stream>>>(E, out + OUT_IDX,
                                                     out + OUT_ZQ);

    scan_kernel<<<1, 1024, 0, stream>>>(cluster_size, ws + WS_C8,
                                        out + OUT_NEWCS, ws + WS_CS,
                                        (int*)(ws + WS_CUR8));

    scatter_kernel<<<N_PTS / 256, 256, 0, stream>>>(out + OUT_IDX,
                                                    (int*)(ws + WS_CUR8),
                                                    (int*)(ws + WS_ORDER));

    segsum_kernel<<<N_PTS / 256, 256, 0, stream>>>(z,
                                                   (const int*)(ws + WS_ORDER),
                                                   ws + WS_EMBSUM);

    ema2_kernel<<<K_CODES * DIM / 256, 256, 0, stream>>>(ema, ws + WS_EMBSUM,
                                                         ws + WS_CS,
                                                         ws + WS_LOSS,
                                                         out + OUT_NEWEMA,
                                                         out + OUT_NEWEMB,
                                                         out + OUT_LOSS);
}